// Round 9
// baseline (285.782 us; speedup 1.0000x reference)
//
#include <hip/hip_runtime.h>
#include <hip/hip_fp16.h>
#include <stdint.h>

#define TT 500
#define HT 250            // steps per direction
#define NB 32
#define RS 1024
#define CD 5120
#define LT 400
#define NC 396
#define NEGF (-1e30f)
#define L2E 1.4426950408889634f
#define LN2f 0.6931471805599453f

#define NRING 5
#define SLAB_B_F32 20480
#define SLAB_B_F16 10240
#define SMEM_MAX (NRING*SLAB_B_F32 + 2*RS*4)   // 110592 B (fp32 fallback)
#define SMEM_F16 (NRING*SLAB_B_F16 + 2*RS*4)   // 59392 B

// fp16 exp-domain image: per slab s=t*32+b (10240 B):
//   planeA: halfs e^f0..e^f7  of group g -> uint4 at byte 16g      (0..4095)
//   planeB: halfs e^f8..e^f15 of group g -> uint4 at 4096+16g      (4096..8191)
//   planeC: halfs e^f16..e^f19 of group g -> uint2 at 8192+8g      (8192..10239)
#define IMG_BYTES 163840000ull                 // 500*32*5120*2

// renorm: multiply alphas by 2^-24 every 8 steps -> 31 renorms over 250 steps
#define RENORM_LOG2 (24.0f * 31.0f)

// float workspace layout (indices into wsf)
#define WS_AT 0
#define WS_BT (NB*RS)
#define WS_AC (2*NB*RS)
#define WS_BC (2*NB*RS + NB*NC)
#define WSF_FLOATS (2*NB*RS + 2*NB*NC)

// Counted-vmcnt phase sync. fp16-exp: 4 stage loads/wave/step -> at sync 12
// outstanding, vmcnt(8) drains step k-3's stage = slab k+1 (read by this
// step's register prefetch). fp32: 5/step -> vmcnt(10).
#define PHASE_SYNC_F16() do {                              \
    __builtin_amdgcn_sched_barrier(0);                     \
    asm volatile("s_waitcnt vmcnt(8) lgkmcnt(0)");         \
    __builtin_amdgcn_s_barrier();                          \
    __builtin_amdgcn_sched_barrier(0);                     \
} while (0)
#define PHASE_SYNC_F32() do {                              \
    __builtin_amdgcn_sched_barrier(0);                     \
    asm volatile("s_waitcnt vmcnt(10) lgkmcnt(0)");        \
    __builtin_amdgcn_s_barrier();                          \
    __builtin_amdgcn_sched_barrier(0);                     \
} while (0)

#define ROT5(x) do { x = (x == 4) ? 0 : x + 1; } while (0)

__device__ __forceinline__ float lse5(float t0,float t1,float t2,float t3,float t4){
    float mx = fmaxf(fmaxf(fmaxf(t0,t1),t2), fmaxf(t3,t4));
    float e = exp2f(t0-mx)+exp2f(t1-mx)+exp2f(t2-mx)+exp2f(t3-mx)+exp2f(t4-mx);
    return mx + log2f(e);
}

// ---- fp32-log-domain step kernels (fallback path) ----
__device__ __forceinline__ void compute4_log(const float (&f)[20], float (&ao)[4],
                                             float p0, float p1, float p2, float p3) {
    ao[0] = lse5(fmaf(f[0],L2E,ao[0]),  fmaf(f[1],L2E,p0),  fmaf(f[2],L2E,p1),
                 fmaf(f[3],L2E,p2),     fmaf(f[4],L2E,p3));
    ao[1] = lse5(fmaf(f[5],L2E,ao[1]),  fmaf(f[6],L2E,p0),  fmaf(f[7],L2E,p1),
                 fmaf(f[8],L2E,p2),     fmaf(f[9],L2E,p3));
    ao[2] = lse5(fmaf(f[10],L2E,ao[2]), fmaf(f[11],L2E,p0), fmaf(f[12],L2E,p1),
                 fmaf(f[13],L2E,p2),    fmaf(f[14],L2E,p3));
    ao[3] = lse5(fmaf(f[15],L2E,ao[3]), fmaf(f[16],L2E,p0), fmaf(f[17],L2E,p1),
                 fmaf(f[18],L2E,p2),    fmaf(f[19],L2E,p3));
}
__device__ __forceinline__ void computeB_log(const float (&f)[20], const float (&st)[4],
                                             float (&bo)[4], float4 bc) {
    bo[0] = lse5(fmaf(st[0],L2E,bo[0]), fmaf(f[1],L2E,bc.x),  fmaf(f[6],L2E,bc.y),
                 fmaf(f[11],L2E,bc.z),  fmaf(f[16],L2E,bc.w));
    bo[1] = lse5(fmaf(st[1],L2E,bo[1]), fmaf(f[2],L2E,bc.x),  fmaf(f[7],L2E,bc.y),
                 fmaf(f[12],L2E,bc.z),  fmaf(f[17],L2E,bc.w));
    bo[2] = lse5(fmaf(st[2],L2E,bo[2]), fmaf(f[3],L2E,bc.x),  fmaf(f[8],L2E,bc.y),
                 fmaf(f[13],L2E,bc.z),  fmaf(f[18],L2E,bc.w));
    bo[3] = lse5(fmaf(st[3],L2E,bo[3]), fmaf(f[4],L2E,bc.x),  fmaf(f[9],L2E,bc.y),
                 fmaf(f[14],L2E,bc.z),  fmaf(f[19],L2E,bc.w));
}

// ---- exp-domain step kernels (fast path): pure mul/fma, no transcendentals ----
__device__ __forceinline__ void compute4_exp(const float (&f)[20], float (&ao)[4],
                                             float p0, float p1, float p2, float p3,
                                             float rs) {
    ao[0] = rs * (fmaf(f[0],ao[0],  f[1]*p0) + fmaf(f[2],p1, f[3]*p2) + f[4]*p3);
    ao[1] = rs * (fmaf(f[5],ao[1],  f[6]*p0) + fmaf(f[7],p1, f[8]*p2) + f[9]*p3);
    ao[2] = rs * (fmaf(f[10],ao[2], f[11]*p0) + fmaf(f[12],p1, f[13]*p2) + f[14]*p3);
    ao[3] = rs * (fmaf(f[15],ao[3], f[16]*p0) + fmaf(f[17],p1, f[18]*p2) + f[19]*p3);
}
__device__ __forceinline__ void computeB_exp(const float (&f)[20], const float (&st)[4],
                                             float (&bo)[4], float4 bc, float rs) {
    bo[0] = rs * (fmaf(st[0],bo[0], f[1]*bc.x)  + fmaf(f[6],bc.y,  f[11]*bc.z) + f[16]*bc.w);
    bo[1] = rs * (fmaf(st[1],bo[1], f[2]*bc.x)  + fmaf(f[7],bc.y,  f[12]*bc.z) + f[17]*bc.w);
    bo[2] = rs * (fmaf(st[2],bo[2], f[3]*bc.x)  + fmaf(f[8],bc.y,  f[13]*bc.z) + f[18]*bc.w);
    bo[3] = rs * (fmaf(st[3],bo[3], f[4]*bc.x)  + fmaf(f[9],bc.y,  f[14]*bc.z) + f[19]*bc.w);
}

// ===================== conversion: fp32 scores -> fp16 e^M image =====================
extern "C" __global__ void __launch_bounds__(256, 1)
convert_exp16(const float* __restrict__ scores, unsigned short* __restrict__ img)
{
    const size_t s = blockIdx.x;
    const int tid = threadIdx.x;
    const float4* p4 = (const float4*)(scores + s*(size_t)CD + 20*tid);
    float4 v0 = p4[0], v1 = p4[1], v2 = p4[2], v3 = p4[3], v4 = p4[4];
    float f[20] = {v0.x,v0.y,v0.z,v0.w, v1.x,v1.y,v1.z,v1.w,
                   v2.x,v2.y,v2.z,v2.w, v3.x,v3.y,v3.z,v3.w,
                   v4.x,v4.y,v4.z,v4.w};
    unsigned q[10];
#pragma unroll
    for (int i = 0; i < 10; ++i) {
        __half2 h = __floats2half2_rn(exp2f(f[2*i] * L2E), exp2f(f[2*i+1] * L2E));
        q[i] = *(unsigned*)&h;
    }
    char* out = (char*)img + s*(size_t)SLAB_B_F16;
    *(uint4*)(out + 16*tid)        = make_uint4(q[0], q[1], q[2], q[3]);
    *(uint4*)(out + 4096 + 16*tid) = make_uint4(q[4], q[5], q[6], q[7]);
    *(uint2*)(out + 8192 + 8*tid)  = make_uint2(q[8], q[9]);
}

// ===================== trellis consumer (templated: fp16-exp vs fp32-log) ====
template<bool E16>
__device__ void trellis(const float* __restrict__ scores,
                        const unsigned short* __restrict__ img,
                        float* __restrict__ wsf, int c, int tid, char* sm)
{
    constexpr int SLAB_B = E16 ? SLAB_B_F16 : SLAB_B_F32;
    const bool is_fwd = c < NB;
    const int b = c & (NB-1);
    const int w = tid >> 6, lane = tid & 63;
    float* A0 = (float*)(sm + NRING*SLAB_B);
    float* A1 = A0 + RS;

    *(float4*)&A0[4*tid] = E16 ? make_float4(1.f,1.f,1.f,1.f)
                               : make_float4(0.f,0.f,0.f,0.f);

    // stage slab t into ring slot: linear copy, HW-verified widths (16B, 4B)
    auto stage = [&](int t, int slot) {
        if constexpr (E16) {
            const char* src = (const char*)img + ((size_t)t*NB + b)*(size_t)SLAB_B_F16 + w*2560;
            char* dst = sm + slot*SLAB_B + w*2560;
            __builtin_amdgcn_global_load_lds(
                (const __attribute__((address_space(1))) void*)(src + lane*16),
                (__attribute__((address_space(3))) void*)(dst), 16, 0, 0);
            __builtin_amdgcn_global_load_lds(
                (const __attribute__((address_space(1))) void*)(src + 1024 + lane*16),
                (__attribute__((address_space(3))) void*)(dst + 1024), 16, 0, 0);
            __builtin_amdgcn_global_load_lds(
                (const __attribute__((address_space(1))) void*)(src + 2048 + lane*4),
                (__attribute__((address_space(3))) void*)(dst + 2048), 4, 0, 0);
            __builtin_amdgcn_global_load_lds(
                (const __attribute__((address_space(1))) void*)(src + 2304 + lane*4),
                (__attribute__((address_space(3))) void*)(dst + 2304), 4, 0, 0);
        } else {
            const char* src = (const char*)(scores + ((size_t)t*NB + b)*(size_t)CD) + w*5120;
            char* dst = sm + slot*SLAB_B + w*5120;
#pragma unroll
            for (int m = 0; m < 5; ++m)
                __builtin_amdgcn_global_load_lds(
                    (const __attribute__((address_space(1))) void*)(src + m*1024 + lane*16),
                    (__attribute__((address_space(3))) void*)(dst + m*1024), 16, 0, 0);
        }
    };

    // register prefetch: 20 transition weights of this thread's state group
    auto rd20 = [&](int slot, float (&f)[20]) {
        const char* sl = sm + slot*SLAB_B;
        if constexpr (E16) {
            uint4 ua = *(const uint4*)(sl + 16*tid);
            uint4 ub = *(const uint4*)(sl + 4096 + 16*tid);
            uint2 uc = *(const uint2*)(sl + 8192 + 8*tid);
            unsigned q[10] = {ua.x,ua.y,ua.z,ua.w, ub.x,ub.y,ub.z,ub.w, uc.x,uc.y};
#pragma unroll
            for (int i = 0; i < 10; ++i) {
                float2 p = __half22float2(*(__half2*)&q[i]);
                f[2*i] = p.x; f[2*i+1] = p.y;
            }
        } else {
            const float4* q4 = (const float4*)(sl + 80*tid);
            float4 r0=q4[0], r1=q4[1], r2=q4[2], r3=q4[3], r4=q4[4];
            f[0]=r0.x; f[1]=r0.y; f[2]=r0.z; f[3]=r0.w;
            f[4]=r1.x; f[5]=r1.y; f[6]=r1.z; f[7]=r1.w;
            f[8]=r2.x; f[9]=r2.y; f[10]=r2.z; f[11]=r2.w;
            f[12]=r3.x; f[13]=r3.y; f[14]=r3.z; f[15]=r3.w;
            f[16]=r4.x; f[17]=r4.y; f[18]=r4.z; f[19]=r4.w;
        }
    };

    // bwd stay weights: original element 5*(tid+256j) -> group g=(tid>>2)+64j,
    // within-group half idx 5*(tid&3) in {0,5,10,15}:
    //   0 -> A 16g+0 ; 5 -> A 16g+10 ; 10 -> B 4096+16g+4 ; 15 -> B 4096+16g+14
    auto rdst = [&](int slot, float (&st)[4]) {
        const char* sl = sm + slot*SLAB_B;
        if constexpr (E16) {
            const int sel = tid & 3;
            int base = (sel == 0) ? 0 : (sel == 1) ? 10 : (sel == 2) ? 4100 : 4110;
#pragma unroll
            for (int j = 0; j < 4; ++j) {
                int g = (tid >> 2) + 64*j;
                st[j] = __half2float(*(const __half*)(sl + base + 16*g));
            }
        } else {
            const float* slf = (const float*)sl;
            st[0] = slf[5*tid];        st[1] = slf[5*tid + 1280];
            st[2] = slf[5*tid + 2560]; st[3] = slf[5*tid + 3840];
        }
    };

    // prologue: stage slabs 0..3 into slots 0..3
#pragma unroll
    for (int p = 0; p < 4; ++p)
        stage(is_fwd ? p : (TT-1-p), p);
    __syncthreads();   // one-time full drain; alpha init visible

    float Ma[20], Mb[20]; float sta[4], stb[4];
    float ao[4];
    ao[0] = ao[1] = ao[2] = ao[3] = E16 ? 1.f : 0.f;
    rd20(0, Ma);
    if (!is_fwd) rdst(0, sta);

    int s_rd = 1, s_st = 4;

    for (int k = 0; k < HT; k += 2) {
        // ===== even step k: A0 -> A1, consume Ma, reg-prefetch slab k+1 =====
        if constexpr (E16) PHASE_SYNC_F16(); else PHASE_SYNC_F32();
        {
            int ts = k + 4; if (ts > HT-1) ts = HT-1;
            stage(is_fwd ? ts : (TT-1-ts), s_st);
        }
        if (is_fwd) {
            float p0 = A0[tid], p1 = A0[tid+256], p2 = A0[tid+512], p3 = A0[tid+768];
            rd20(s_rd, Mb);
            if constexpr (E16) compute4_exp(Ma, ao, p0, p1, p2, p3, 1.0f);
            else               compute4_log(Ma, ao, p0, p1, p2, p3);
            *(float4*)&A1[4*tid] = make_float4(ao[0],ao[1],ao[2],ao[3]);
        } else {
            float4 bc = *(const float4*)&A0[4*tid];
            rd20(s_rd, Mb);
            rdst(s_rd, stb);
            if constexpr (E16) computeB_exp(Ma, sta, ao, bc, 1.0f);
            else               computeB_log(Ma, sta, ao, bc);
            A1[tid] = ao[0]; A1[tid+256] = ao[1]; A1[tid+512] = ao[2]; A1[tid+768] = ao[3];
        }
        ROT5(s_rd); ROT5(s_st);

        // ===== odd step k+1: A1 -> A0, consume Mb, reg-prefetch slab k+2 =====
        if constexpr (E16) PHASE_SYNC_F16(); else PHASE_SYNC_F32();
        {
            int ts = k + 5; if (ts > HT-1) ts = HT-1;
            stage(is_fwd ? ts : (TT-1-ts), s_st);
        }
        {
            // renorm by 2^-24 on steps k+1 = 7,15,...,247 (31 times)
            const float rs = ((k & 7) == 6) ? 0x1p-24f : 1.0f;
            if (is_fwd) {
                float p0 = A1[tid], p1 = A1[tid+256], p2 = A1[tid+512], p3 = A1[tid+768];
                rd20(s_rd, Ma);
                if constexpr (E16) compute4_exp(Mb, ao, p0, p1, p2, p3, rs);
                else               compute4_log(Mb, ao, p0, p1, p2, p3);
                *(float4*)&A0[4*tid] = make_float4(ao[0],ao[1],ao[2],ao[3]);
            } else {
                float4 bc = *(const float4*)&A1[4*tid];
                rd20(s_rd, Ma);
                rdst(s_rd, sta);
                if constexpr (E16) computeB_exp(Mb, stb, ao, bc, rs);
                else               computeB_log(Mb, stb, ao, bc);
                A0[tid] = ao[0]; A0[tid+256] = ao[1]; A0[tid+512] = ao[2]; A0[tid+768] = ao[3];
            }
        }
        ROT5(s_rd); ROT5(s_st);
    }

    // epilogue: convert to log2 domain (+ renorm offset) and store
    float o0, o1, o2, o3;
    if constexpr (E16) {
        o0 = log2f(ao[0]) + RENORM_LOG2; o1 = log2f(ao[1]) + RENORM_LOG2;
        o2 = log2f(ao[2]) + RENORM_LOG2; o3 = log2f(ao[3]) + RENORM_LOG2;
    } else { o0 = ao[0]; o1 = ao[1]; o2 = ao[2]; o3 = ao[3]; }

    if (is_fwd) {
        *(float4*)&wsf[WS_AT + b*RS + 4*tid] = make_float4(o0,o1,o2,o3);
    } else {
        wsf[WS_BT + b*RS + tid]       = o0;
        wsf[WS_BT + b*RS + tid + 256] = o1;
        wsf[WS_BT + b*RS + tid + 512] = o2;
        wsf[WS_BT + b*RS + tid + 768] = o3;
    }
}

// ===================== banded CTC (one wave per block, fp32 gathers) =====================
__device__ __forceinline__ void ldc(const float* __restrict__ p,
                                    const int (&so)[7], const int (&mo)[7],
                                    float (&S)[7], float (&V)[7]) {
#pragma unroll
    for (int k = 0; k < 7; ++k) { S[k] = p[so[k]]; V[k] = p[mo[k]]; }
}

__device__ __forceinline__ void cstep(const float (&S)[7], const float (&V)[7],
                                      float (&ac)[7], int lane) {
    float prev = __shfl_up(ac[6], 1, 64);
    float nw[7];
#pragma unroll
    for (int k = 0; k < 7; ++k) {
        float left = k ? ac[k-1] : prev;
        float x = fmaf(S[k], L2E, ac[k]);
        float y = fmaf(V[k], L2E, left);
        if (k == 0) y = (lane == 0) ? NEGF : y;
        float m2 = fmaxf(x, y);
        float d  = fminf(x, y) - m2;
        nw[k] = m2 + log2f(1.0f + exp2f(d));
    }
#pragma unroll
    for (int k = 0; k < 7; ++k) ac[k] = nw[k];
}

__device__ __forceinline__ void cstep_b(const float (&S)[7], const float (&V)[7],
                                        float (&ac)[7], int lane) {
    float nxt = __shfl_down(ac[0], 1, 64);
    float nw[7];
#pragma unroll
    for (int k = 0; k < 7; ++k) {
        int gi = 7*lane + k;
        float bn = (k < 6) ? ac[k+1] : nxt;
        float x = fmaf(S[k], L2E, ac[k]);
        float y = fmaf(V[k], L2E, bn);
        y = (gi < NC-1) ? y : NEGF;
        float m2 = fmaxf(x, y);
        float d  = fminf(x, y) - m2;
        float r  = m2 + log2f(1.0f + exp2f(d));
        nw[k] = (gi < NC) ? r : NEGF;
    }
#pragma unroll
    for (int k = 0; k < 7; ++k) ac[k] = nw[k];
}

__device__ void build_tloc(const int* __restrict__ targets, int b, int lane, int (&tloc)[12]) {
#pragma unroll
    for (int j = 0; j < 12; ++j) {
        int gi = 7*lane - 1 + j;
        gi = gi < 0 ? 0 : (gi > LT-1 ? LT-1 : gi);
        int v = targets[b*LT + gi] - 1;
        tloc[j] = v < 0 ? 0 : v;
    }
}

__device__ void ctc_fwd(const float* __restrict__ scores, const int* __restrict__ targets,
                        float* __restrict__ wsf, int b, int lane) {
    int tloc[12]; build_tloc(targets, b, lane, tloc);
    int so[7], mo[7];
#pragma unroll
    for (int k = 0; k < 7; ++k) {
        int gi = 7*lane + k;
        if (gi < NC) {
            int K = tloc[k+1];
            K = K*4 + tloc[k+2]; K = K*4 + tloc[k+3];
            K = K*4 + tloc[k+4]; K = K*4 + tloc[k+5];
            so[k] = K*5;
            mo[k] = (gi >= 1) ? (so[k] + tloc[k] + 1) : 0;
        } else { so[k] = 0; mo[k] = 0; }
    }
    float ac[7];
#pragma unroll
    for (int k = 0; k < 7; ++k) ac[k] = (7*lane + k == 0) ? 0.f : NEGF;

    const size_t STP = (size_t)NB*CD;
    const float* q0 = scores + (size_t)b*CD;
    const float* q1 = q0 + STP; const float* q2 = q0 + 2*STP; const float* q3 = q0 + 3*STP;
    float S0[7],V0[7],S1[7],V1[7],S2[7],V2[7],S3[7],V3[7];
    ldc(q0,so,mo,S0,V0); ldc(q1,so,mo,S1,V1); ldc(q2,so,mo,S2,V2); ldc(q3,so,mo,S3,V3);
    for (int t = 0; t < HT-2; t += 4) {
        cstep(S0,V0,ac,lane); if (t+4 < HT) { q0 += 4*STP; ldc(q0,so,mo,S0,V0); }
        cstep(S1,V1,ac,lane); if (t+5 < HT) { q1 += 4*STP; ldc(q1,so,mo,S1,V1); }
        cstep(S2,V2,ac,lane); if (t+6 < HT) { q2 += 4*STP; ldc(q2,so,mo,S2,V2); }
        cstep(S3,V3,ac,lane); if (t+7 < HT) { q3 += 4*STP; ldc(q3,so,mo,S3,V3); }
    }
    cstep(S0,V0,ac,lane);
    cstep(S1,V1,ac,lane);
#pragma unroll
    for (int k = 0; k < 7; ++k) {
        int gi = 7*lane + k;
        if (gi < NC) wsf[WS_AC + b*NC + gi] = ac[k];
    }
}

__device__ void ctc_bwd(const float* __restrict__ scores, const int* __restrict__ targets,
                        const int* __restrict__ tlens, float* __restrict__ wsf, int b, int lane) {
    int tloc[12]; build_tloc(targets, b, lane, tloc);
    int so[7], vo[7];
#pragma unroll
    for (int k = 0; k < 7; ++k) {
        int gi = 7*lane + k;
        if (gi < NC) {
            int K = tloc[k+1];
            K = K*4 + tloc[k+2]; K = K*4 + tloc[k+3];
            K = K*4 + tloc[k+4]; K = K*4 + tloc[k+5];
            so[k] = K*5;
            if (gi < NC-1) {
                int K2 = tloc[k+2];
                K2 = K2*4 + tloc[k+3]; K2 = K2*4 + tloc[k+4];
                K2 = K2*4 + tloc[k+5]; K2 = K2*4 + tloc[k+6];
                vo[k] = K2*5 + tloc[k+1] + 1;
            } else vo[k] = 0;
        } else { so[k] = 0; vo[k] = 0; }
    }
    int tl = tlens[b];
    float ac[7];
#pragma unroll
    for (int k = 0; k < 7; ++k) ac[k] = (7*lane + k == tl-5) ? 0.f : NEGF;

    const size_t STP = (size_t)NB*CD;
    const float* q0 = scores + ((size_t)(TT-1)*NB + b)*CD;
    const float* q1 = q0 - STP; const float* q2 = q0 - 2*STP; const float* q3 = q0 - 3*STP;
    float S0[7],V0[7],S1[7],V1[7],S2[7],V2[7],S3[7],V3[7];
    ldc(q0,so,vo,S0,V0); ldc(q1,so,vo,S1,V1); ldc(q2,so,vo,S2,V2); ldc(q3,so,vo,S3,V3);
    for (int p = 0; p < HT-2; p += 4) {
        cstep_b(S0,V0,ac,lane); if (p+4 < HT) { q0 -= 4*STP; ldc(q0,so,vo,S0,V0); }
        cstep_b(S1,V1,ac,lane); if (p+5 < HT) { q1 -= 4*STP; ldc(q1,so,vo,S1,V1); }
        cstep_b(S2,V2,ac,lane); if (p+6 < HT) { q2 -= 4*STP; ldc(q2,so,vo,S2,V2); }
        cstep_b(S3,V3,ac,lane); if (p+7 < HT) { q3 -= 4*STP; ldc(q3,so,vo,S3,V3); }
    }
    cstep_b(S0,V0,ac,lane);
    cstep_b(S1,V1,ac,lane);
#pragma unroll
    for (int k = 0; k < 7; ++k) {
        int gi = 7*lane + k;
        if (gi < NC) wsf[WS_BC + b*NC + gi] = ac[k];
    }
}

// ===================== kernels =====================
extern "C" __global__ void __launch_bounds__(256, 1)
ctc_crf_main(const float* __restrict__ scores, const unsigned short* __restrict__ img,
             const int* __restrict__ targets, const int* __restrict__ tlens,
             float* __restrict__ wsf, int useE16)
{
    extern __shared__ float smf[];
    char* sm = (char*)smf;
    const int tid = threadIdx.x, blk = blockIdx.x;

    if (blk < 2*NB) {
        if (useE16) trellis<true>(scores, img, wsf, blk, tid, sm);
        else        trellis<false>(scores, img, wsf, blk, tid, sm);
        return;
    }
    if (tid >= 64) return;
    if (blk < 3*NB) ctc_fwd(scores, targets, wsf, blk - 2*NB, tid);
    else            ctc_bwd(scores, targets, tlens, wsf, blk - 3*NB, tid);
}

extern "C" __global__ void __launch_bounds__(256, 1)
ctc_crf_combine(const float* __restrict__ wsf, const int* __restrict__ tlens,
                float* __restrict__ out)
{
    const int b = blockIdx.x, tid = threadIdx.x, lane = tid & 63, w = tid >> 6;
    __shared__ float r1[4], r2[4];

    float4 a4 = *(const float4*)&wsf[WS_AT + b*RS + 4*tid];
    float4 b4 = *(const float4*)&wsf[WS_BT + b*RS + 4*tid];
    float v0 = a4.x+b4.x, v1 = a4.y+b4.y, v2 = a4.z+b4.z, v3 = a4.w+b4.w;
    float m = fmaxf(fmaxf(v0,v1), fmaxf(v2,v3));
#pragma unroll
    for (int o = 32; o >= 1; o >>= 1) m = fmaxf(m, __shfl_xor(m, o, 64));
    if (lane == 0) r1[w] = m;
    __syncthreads();
    float g = fmaxf(fmaxf(r1[0],r1[1]), fmaxf(r1[2],r1[3]));
    float e = exp2f(v0-g)+exp2f(v1-g)+exp2f(v2-g)+exp2f(v3-g);
#pragma unroll
    for (int o = 32; o >= 1; o >>= 1) e += __shfl_xor(e, o, 64);
    if (lane == 0) r2[w] = e;
    __syncthreads();
    float zfull = g + log2f(r2[0]+r2[1]+r2[2]+r2[3]);
    __syncthreads();

    float c0 = (tid < NC)     ? wsf[WS_AC + b*NC + tid]       + wsf[WS_BC + b*NC + tid]       : NEGF;
    float c1 = (tid+256 < NC) ? wsf[WS_AC + b*NC + tid + 256] + wsf[WS_BC + b*NC + tid + 256] : NEGF;
    float mc = fmaxf(c0, c1);
#pragma unroll
    for (int o = 32; o >= 1; o >>= 1) mc = fmaxf(mc, __shfl_xor(mc, o, 64));
    if (lane == 0) r1[w] = mc;
    __syncthreads();
    float gc = fmaxf(fmaxf(r1[0],r1[1]), fmaxf(r1[2],r1[3]));
    float ec = exp2f(c0-gc)+exp2f(c1-gc);
#pragma unroll
    for (int o = 32; o >= 1; o >>= 1) ec += __shfl_xor(ec, o, 64);
    if (lane == 0) r2[w] = ec;
    __syncthreads();
    if (tid == 0) {
        float zctc = gc + log2f(r2[0]+r2[1]+r2[2]+r2[3]);
        int tl = tlens[b];
        float loss_b = LN2f * (zfull - zctc) / (float)tl;
        atomicAdd(out, loss_b / (float)NB);
    }
}

extern "C" void kernel_launch(void* const* d_in, const int* in_sizes, int n_in,
                              void* d_out, int out_size, void* d_ws, size_t ws_size,
                              hipStream_t stream) {
    const float* scores  = (const float*)d_in[0];
    const int*   targets = (const int*)d_in[1];
    const int*   tlens   = (const int*)d_in[2];
    float* out = (float*)d_out;

    const size_t need = IMG_BYTES + (size_t)WSF_FLOATS*4 + 1024;
    const int useE16 = (ws_size >= need) ? 1 : 0;
    unsigned short* img = (unsigned short*)d_ws;
    float* wsf = useE16 ? (float*)((char*)d_ws + IMG_BYTES) : (float*)d_ws;

    hipFuncSetAttribute((const void*)ctc_crf_main,
                        hipFuncAttributeMaxDynamicSharedMemorySize, SMEM_MAX);
    hipMemsetAsync(out, 0, sizeof(float), stream);
    if (useE16)
        convert_exp16<<<TT*NB, 256, 0, stream>>>(scores, img);
    ctc_crf_main<<<4*NB, 256, useE16 ? SMEM_F16 : SMEM_MAX, stream>>>(
        scores, img, targets, tlens, wsf, useE16);
    ctc_crf_combine<<<NB, 256, 0, stream>>>(wsf, tlens, out);
}